// Round 6
// baseline (4526.912 us; speedup 1.0000x reference)
//
#include <hip/hip_runtime.h>
#include <stdint.h>

// Forbid mul+add contraction: distance arithmetic must match the numpy
// reference bit-for-bit (argmax / radius-compare are discontinuous).
// MLP math uses explicit fmaf() (exact FMA is fine; only ordering matters).
#pragma clang fp contract(off)

#define NPT   16384
#define BB    8
#define SS    1024
#define KSAMP 32
#define PTOT  (BB*SS*KSAMP)   // 262144
#define NGRP  (BB*SS)         // 8192
#define R2    0.04f
#define EPSBN 1e-5f
#define INV_M 3.814697265625e-06f   // 1/262144, exact power of two

// ws layout (floats)
#define OFF_S1 0
#define OFF_Q1 64
#define OFF_S2 128
#define OFF_Q2 192
#define OFF_S3 256    // 128
#define OFF_Q3 384    // 128
#define OFF_A1 512
#define OFF_C1 576
#define OFF_A2 640
#define OFF_C2 704
#define OFF_A3 768    // 128
#define OFF_C3 896    // 128
#define OFF_ZMAX 1024                  // 8192*128 = 1048576
#define OFF_FEAT (1024 + 1048576)      // 6*262144 = 1572864  (total ~10.5 MB)
// fps binned-point scratch ALIASES the feat region (2 MB of its 6 MB): fps
// finishes before ballq writes feat, so no extra ws is needed.

// ---------------------------------------------------------------------------
// helpers
// ---------------------------------------------------------------------------
__device__ __forceinline__ float wave_sum(float v) {
#pragma unroll
  for (int off = 32; off; off >>= 1) v += __shfl_xor(v, off);
  return v;
}
__device__ __forceinline__ float half_max(float v) {
#pragma unroll
  for (int off = 16; off; off >>= 1) v = fmaxf(v, __shfl_xor(v, off));
  return v;
}
// (d >= 0, ~idx) packed: lexicographic max == (max d, first orig index)
__device__ __forceinline__ unsigned long long pack_di(float d, int idx) {
  return ((unsigned long long)__float_as_uint(d) << 32) |
         (unsigned int)(~(unsigned int)idx);
}
__device__ __forceinline__ unsigned long long u64max(unsigned long long a,
                                                     unsigned long long b) {
  return a > b ? a : b;
}

// ---------------------------------------------------------------------------
// 1) FPS, exact + bucket-pruned (R5 algorithm), LATENCY-FLATTENED schedule.
//    R5 post-mortem: per-bucket serial chain (~900cyc: L2 load + LDS RMW +
//    butterfly) x ~5 buckets/wave = 2.8us/iter, VALUBusy 0.9%. Fixes:
//    (a) 4 buckets in flight per wave, stage-interleaved (loads | d-update |
//        butterflies interleaved) -> chains overlap;
//    (b) u64 packed (dbits<<32 | ~idx): one butterfly gives exact
//        (max d, first index); bound for skip test = high 32 bits; stale
//        packed stays EXACT for skipped buckets (skip => d unchanged);
//    (c) C split: waves 0-7 reduce 512 packed -> 8 partials; next phase all
//        threads merge partials redundantly -> fi known everywhere, still
//        3 barriers/iter.
//    d[] bit-identical to brute force (fminf exact, skip provably no-op).
// ---------------------------------------------------------------------------
__global__ __launch_bounds__(1024, 4)
void fps_kernel(const float* __restrict__ xyz, float* __restrict__ newxyz,
                float4* __restrict__ bpt) {
  const int b = blockIdx.x;
  const int t = threadIdx.x;
  const int lane = t & 63;
  const int w = t >> 6;                 // 16 waves
  const float* xb = xyz + (size_t)b * NPT * 3;
  float4* bp = bpt + (size_t)b * NPT;

  __shared__ float dlds[NPT];                                   // 64 KB
  __shared__ float bminx[512], bminy[512], bminz[512];
  __shared__ float bmaxx[512], bmaxy[512], bmaxz[512];          // 12 KB
  __shared__ unsigned long long packed[512];                    // 4 KB
  __shared__ int   cntb[512], startb[512], curb[512];
  __shared__ int   list[512];
  __shared__ unsigned long long partial[8];
  __shared__ int   nact[2];

  // ---- setup: bin into 8x8x8 cells (binning affects speed only) ----
  if (t < 512) cntb[t] = 0;
  if (t == 0) { nact[0] = 0; nact[1] = 0; }
  __syncthreads();
  int mycell[16];
#pragma unroll
  for (int k = 0; k < 16; ++k) {
    int p = k * 1024 + t;
    float px = xb[3 * p], py = xb[3 * p + 1], pz = xb[3 * p + 2];
    int ix = min(7, max(0, (int)(px * 8.0f)));
    int iy = min(7, max(0, (int)(py * 8.0f)));
    int iz = min(7, max(0, (int)(pz * 8.0f)));
    int cell = (ix << 6) | (iy << 3) | iz;
    mycell[k] = cell;
    atomicAdd(&cntb[cell], 1);
  }
  __syncthreads();
  if (t == 0) {
    int acc = 0;
    for (int i = 0; i < 512; ++i) { startb[i] = acc; curb[i] = acc; acc += cntb[i]; }
  }
  __syncthreads();
#pragma unroll
  for (int k = 0; k < 16; ++k) {
    int p = k * 1024 + t;
    int pos = atomicAdd(&curb[mycell[k]], 1);
    bp[pos] = make_float4(xb[3 * p], xb[3 * p + 1], xb[3 * p + 2], __int_as_float(p));
  }
  for (int i = t; i < NPT; i += 1024) dlds[i] = 1e10f;
  __syncthreads();
  for (int bk = w; bk < 512; bk += 16) {        // member-exact bboxes
    int st = startb[bk], cn = cntb[bk];
    float mnx = 1e30f, mny = 1e30f, mnz = 1e30f;
    float mxx = -1e30f, mxy = -1e30f, mxz = -1e30f;
    for (int l = lane; l < cn; l += 64) {
      float4 q = bp[st + l];
      mnx = fminf(mnx, q.x); mny = fminf(mny, q.y); mnz = fminf(mnz, q.z);
      mxx = fmaxf(mxx, q.x); mxy = fmaxf(mxy, q.y); mxz = fmaxf(mxz, q.z);
    }
#pragma unroll
    for (int off = 32; off; off >>= 1) {
      mnx = fminf(mnx, __shfl_xor(mnx, off)); mny = fminf(mny, __shfl_xor(mny, off));
      mnz = fminf(mnz, __shfl_xor(mnz, off)); mxx = fmaxf(mxx, __shfl_xor(mxx, off));
      mxy = fmaxf(mxy, __shfl_xor(mxy, off)); mxz = fmaxf(mxz, __shfl_xor(mxz, off));
    }
    if (lane == 0) {
      bminx[bk] = mnx; bminy[bk] = mny; bminz[bk] = mnz;
      bmaxx[bk] = mxx; bmaxy[bk] = mxy; bmaxz[bk] = mxz;
      packed[bk] = (cn > 0) ? pack_di(1e10f, 0) : 0ull;  // empty: never wins
    }
  }
  if (t == 0) {                         // idx[0] = 0
    float* o = newxyz + (size_t)b * SS * 3;
    o[0] = xb[0]; o[1] = xb[1]; o[2] = xb[2];
  }
  __syncthreads();

  int fi = 0;
  for (int s = 1; s < SS; ++s) {
    // ---- C1: waves 0-7 reduce packed[512] -> partial[w]  (s>1) ----
    if (s > 1 && w < 8) {
      unsigned long long pk = packed[t];          // t < 512 here
#pragma unroll
      for (int off = 32; off; off >>= 1)
        pk = u64max(pk, __shfl_xor(pk, off));
      if (lane == 0) partial[w] = pk;
    }
    __syncthreads();                              // bar A

    // ---- C2 (all threads, redundant) + A (waves 0-7) ----
    if (s > 1) {
      unsigned long long best = partial[0];
#pragma unroll
      for (int ww = 1; ww < 8; ++ww) best = u64max(best, partial[ww]);
      fi = (int)(~(unsigned int)(best & 0xffffffffull));
      if (t == 0) {
        float* o = newxyz + ((size_t)b * SS + (s - 1)) * 3;
        o[0] = xb[3 * fi]; o[1] = xb[3 * fi + 1]; o[2] = xb[3 * fi + 2];
      }
    }
    float cx = xb[3 * fi], cy = xb[3 * fi + 1], cz = xb[3 * fi + 2];
    if (t == 0) nact[(s + 1) & 1] = 0;            // slot for A(s+1)
    if (t < 512) {
      float lx = fmaxf(0.0f, fmaxf(bminx[t] - cx, cx - bmaxx[t]));
      float ly = fmaxf(0.0f, fmaxf(bminy[t] - cy, cy - bmaxy[t]));
      float lz = fmaxf(0.0f, fmaxf(bminz[t] - cz, cz - bmaxz[t]));
      float lb2 = (lx * lx + ly * ly) + lz * lz;
      float bnd = __uint_as_float((unsigned int)(packed[t] >> 32));
      bool ok = (lb2 * 0.999f <= bnd);            // conservative margin
      uint64_t m = __ballot(ok);
      int cw = (int)__popcll(m);
      int base = 0;
      if (lane == 0 && cw) base = atomicAdd(&nact[s & 1], cw);
      base = __shfl(base, 0);
      if (ok) list[base + (int)__popcll(m & ((1ull << lane) - 1ull))] = t;
    }
    __syncthreads();                              // bar B

    // ---- B: 4 buckets in flight per wave, stage-interleaved ----
    int na = nact[s & 1];
    for (int base = 0; base < na; base += 64) {
      bool v0 = (base + w) < na,            v1 = (base + 16 + w) < na;
      bool v2 = (base + 32 + w) < na,       v3 = (base + 48 + w) < na;
      int bk0 = v0 ? list[base + w] : 0,       bk1 = v1 ? list[base + 16 + w] : 0;
      int bk2 = v2 ? list[base + 32 + w] : 0,  bk3 = v3 ? list[base + 48 + w] : 0;
      int st0 = startb[bk0], cn0 = cntb[bk0];
      int st1 = startb[bk1], cn1 = cntb[bk1];
      int st2 = startb[bk2], cn2 = cntb[bk2];
      int st3 = startb[bk3], cn3 = cntb[bk3];
      float4 q0, q1, q2, q3;                       // stage 1: all loads
      if (v0 && lane < cn0) q0 = bp[st0 + lane];
      if (v1 && lane < cn1) q1 = bp[st1 + lane];
      if (v2 && lane < cn2) q2 = bp[st2 + lane];
      if (v3 && lane < cn3) q3 = bp[st3 + lane];
      unsigned long long p0 = 0, p1 = 0, p2 = 0, p3 = 0;
      // stage 2: d-updates (independent across j, chains overlap)
      if (v0 && lane < cn0) {
        float dx = q0.x - cx, dy = q0.y - cy, dz = q0.z - cz;
        float d2 = (dx * dx + dy * dy) + dz * dz;
        float dn = fminf(dlds[st0 + lane], d2);
        dlds[st0 + lane] = dn;
        p0 = pack_di(dn, __float_as_int(q0.w));
      }
      if (v1 && lane < cn1) {
        float dx = q1.x - cx, dy = q1.y - cy, dz = q1.z - cz;
        float d2 = (dx * dx + dy * dy) + dz * dz;
        float dn = fminf(dlds[st1 + lane], d2);
        dlds[st1 + lane] = dn;
        p1 = pack_di(dn, __float_as_int(q1.w));
      }
      if (v2 && lane < cn2) {
        float dx = q2.x - cx, dy = q2.y - cy, dz = q2.z - cz;
        float d2 = (dx * dx + dy * dy) + dz * dz;
        float dn = fminf(dlds[st2 + lane], d2);
        dlds[st2 + lane] = dn;
        p2 = pack_di(dn, __float_as_int(q2.w));
      }
      if (v3 && lane < cn3) {
        float dx = q3.x - cx, dy = q3.y - cy, dz = q3.z - cz;
        float d2 = (dx * dx + dy * dy) + dz * dz;
        float dn = fminf(dlds[st3 + lane], d2);
        dlds[st3 + lane] = dn;
        p3 = pack_di(dn, __float_as_int(q3.w));
      }
      // residual points (cn > 64): essentially never (Poisson mean 32)
      if (v0) for (int l = 64 + lane; l < cn0; l += 64) {
        float4 q = bp[st0 + l];
        float dx = q.x - cx, dy = q.y - cy, dz = q.z - cz;
        float d2 = (dx * dx + dy * dy) + dz * dz;
        float dn = fminf(dlds[st0 + l], d2);
        dlds[st0 + l] = dn;
        p0 = u64max(p0, pack_di(dn, __float_as_int(q.w)));
      }
      if (v1) for (int l = 64 + lane; l < cn1; l += 64) {
        float4 q = bp[st1 + l];
        float dx = q.x - cx, dy = q.y - cy, dz = q.z - cz;
        float d2 = (dx * dx + dy * dy) + dz * dz;
        float dn = fminf(dlds[st1 + l], d2);
        dlds[st1 + l] = dn;
        p1 = u64max(p1, pack_di(dn, __float_as_int(q.w)));
      }
      if (v2) for (int l = 64 + lane; l < cn2; l += 64) {
        float4 q = bp[st2 + l];
        float dx = q.x - cx, dy = q.y - cy, dz = q.z - cz;
        float d2 = (dx * dx + dy * dy) + dz * dz;
        float dn = fminf(dlds[st2 + l], d2);
        dlds[st2 + l] = dn;
        p2 = u64max(p2, pack_di(dn, __float_as_int(q.w)));
      }
      if (v3) for (int l = 64 + lane; l < cn3; l += 64) {
        float4 q = bp[st3 + l];
        float dx = q.x - cx, dy = q.y - cy, dz = q.z - cz;
        float d2 = (dx * dx + dy * dy) + dz * dz;
        float dn = fminf(dlds[st3 + l], d2);
        dlds[st3 + l] = dn;
        p3 = u64max(p3, pack_di(dn, __float_as_int(q.w)));
      }
      // stage 3: four butterflies, step-interleaved (latency overlap)
#pragma unroll
      for (int off = 32; off; off >>= 1) {
        unsigned long long o0 = __shfl_xor(p0, off);
        unsigned long long o1 = __shfl_xor(p1, off);
        unsigned long long o2 = __shfl_xor(p2, off);
        unsigned long long o3 = __shfl_xor(p3, off);
        p0 = u64max(p0, o0); p1 = u64max(p1, o1);
        p2 = u64max(p2, o2); p3 = u64max(p3, o3);
      }
      // stage 4: writeback (one wave owns each bucket; no atomics)
      if (lane == 0) {
        if (v0) packed[bk0] = p0;
        if (v1) packed[bk1] = p1;
        if (v2) packed[bk2] = p2;
        if (v3) packed[bk3] = p3;
      }
    }
    __syncthreads();                              // bar C
  }

  // ---- final: idx[1023] ----
  if (w < 8) {
    unsigned long long pk = packed[t];
#pragma unroll
    for (int off = 32; off; off >>= 1)
      pk = u64max(pk, __shfl_xor(pk, off));
    if (lane == 0) partial[w] = pk;
  }
  __syncthreads();
  if (t == 0) {
    unsigned long long best = partial[0];
#pragma unroll
    for (int ww = 1; ww < 8; ++ww) best = u64max(best, partial[ww]);
    int fl = (int)(~(unsigned int)(best & 0xffffffffull));
    float* o = newxyz + ((size_t)b * SS + (SS - 1)) * 3;
    o[0] = xb[3 * fl]; o[1] = xb[3 * fl + 1]; o[2] = xb[3 * fl + 2];
  }
}

// ---------------------------------------------------------------------------
// 2) Ball query + gather (fused): one wave per centroid, ascending-index scan
//    with ballot == ref's sort+slice. feat is channel-major [6][PTOT].
// ---------------------------------------------------------------------------
__global__ __launch_bounds__(256, 2)
void ballq_kernel(const float* __restrict__ xyz, const float* __restrict__ pts,
                  const float* __restrict__ newxyz, float* __restrict__ feat) {
  const int lane = threadIdx.x & 63;
  const int c = blockIdx.x * 4 + (threadIdx.x >> 6);  // 0..8191
  const int b = c >> 10;
  const float* xb = xyz + (size_t)b * NPT * 3;
  const float* pb = pts + (size_t)b * NPT * 3;
  const float cx = newxyz[3 * c], cy = newxyz[3 * c + 1], cz = newxyz[3 * c + 2];
  const int base = c * KSAMP;
  const uint64_t ltm = (1ull << lane) - 1ull;

  int cnt = 0, firstp = 0;
  bool haveFirst = false;
  for (int p0 = 0; p0 < NPT && cnt < KSAMP; p0 += 64) {
    int p = p0 + lane;
    float px = xb[3 * p], py = xb[3 * p + 1], pz = xb[3 * p + 2];
    float dx = cx - px, dy = cy - py, dz = cz - pz;
    float sqr = (dx * dx + dy * dy) + dz * dz;
    bool in = (sqr <= R2);                          // !(sqr > r^2)
    uint64_t m = __ballot(in);
    if (!haveFirst && m) { firstp = p0 + (__ffsll((unsigned long long)m) - 1); haveFirst = true; }
    int rank = (int)__popcll(m & ltm);
    int slot = cnt + rank;
    if (in && slot < KSAMP) {
      int idx = base + slot;
      feat[0 * PTOT + idx] = px - cx;
      feat[1 * PTOT + idx] = py - cy;
      feat[2 * PTOT + idx] = pz - cz;
      feat[3 * PTOT + idx] = pb[3 * p];
      feat[4 * PTOT + idx] = pb[3 * p + 1];
      feat[5 * PTOT + idx] = pb[3 * p + 2];
    }
    cnt += (int)__popcll(m);
  }
  if (cnt < KSAMP) {  // pad with first in-ball point (center itself qualifies)
    int slot = cnt + lane;
    if (slot < KSAMP) {
      int idx = base + slot;
      float px = xb[3 * firstp], py = xb[3 * firstp + 1], pz = xb[3 * firstp + 2];
      feat[0 * PTOT + idx] = px - cx;
      feat[1 * PTOT + idx] = py - cy;
      feat[2 * PTOT + idx] = pz - cz;
      feat[3 * PTOT + idx] = pb[3 * firstp];
      feat[4 * PTOT + idx] = pb[3 * firstp + 1];
      feat[5 * PTOT + idx] = pb[3 * firstp + 2];
    }
  }
}

// ---------------------------------------------------------------------------
// 3) stats of layer-1 pre-activations.
// ---------------------------------------------------------------------------
__global__ __launch_bounds__(256, 2)
void mlp1s_kernel(const float* __restrict__ feat, const float* __restrict__ w0,
                  const float* __restrict__ b0, float* __restrict__ stats) {
  float s[64], q[64];
#pragma unroll
  for (int o = 0; o < 64; ++o) { s[o] = 0.0f; q[o] = 0.0f; }
  int gid = blockIdx.x * 256 + threadIdx.x;
  for (int p = gid; p < PTOT; p += 256 * 256) {
    float f[6];
#pragma unroll
    for (int ch = 0; ch < 6; ++ch) f[ch] = feat[ch * PTOT + p];
#pragma unroll
    for (int o = 0; o < 64; ++o) {
      float z = b0[o];
#pragma unroll
      for (int i = 0; i < 6; ++i) z = fmaf(w0[o * 6 + i], f[i], z);
      s[o] += z; q[o] = fmaf(z, z, q[o]);
    }
  }
  const int lane = threadIdx.x & 63;
#pragma unroll
  for (int o = 0; o < 64; ++o) { s[o] = wave_sum(s[o]); q[o] = wave_sum(q[o]); }
  __shared__ float ls[128];
  if (threadIdx.x < 128) ls[threadIdx.x] = 0.0f;
  __syncthreads();
  if (lane == 0) {
#pragma unroll
    for (int o = 0; o < 64; ++o) { atomicAdd(&ls[o], s[o]); atomicAdd(&ls[64 + o], q[o]); }
  }
  __syncthreads();
  if (threadIdx.x < 64) atomicAdd(&stats[OFF_S1 + threadIdx.x], ls[threadIdx.x]);
  else if (threadIdx.x < 128) atomicAdd(&stats[OFF_Q1 + threadIdx.x - 64], ls[threadIdx.x]);
}

// ---------------------------------------------------------------------------
// BN fold: a = g/sqrt(var+eps), c = be - a*mu   (h = relu(a*z + c))
// ---------------------------------------------------------------------------
__global__ void fin_kernel(const float* __restrict__ g, const float* __restrict__ be,
                           const float* __restrict__ s, const float* __restrict__ q,
                           float* __restrict__ A, float* __restrict__ C, int Cn) {
  int o = blockIdx.x * blockDim.x + threadIdx.x;
  if (o >= Cn) return;
  float mu = s[o] * INV_M;
  float var = q[o] * INV_M - mu * mu;
  float a = g[o] / sqrtf(var + EPSBN);
  A[o] = a;
  C[o] = be[o] - a * mu;
}

// ---------------------------------------------------------------------------
// 4) stats of layer-2 pre-activations.
// ---------------------------------------------------------------------------
__global__ __launch_bounds__(256, 2)
void mlp2s_kernel(const float* __restrict__ feat,
                  const float* __restrict__ w0, const float* __restrict__ b0,
                  const float* __restrict__ w1, const float* __restrict__ b1,
                  const float* __restrict__ par, float* __restrict__ stats) {
  const float* a1 = par + OFF_A1;
  const float* c1 = par + OFF_C1;
  const int lane = threadIdx.x & 63;
  float sp = 0.0f, qp = 0.0f;
  int gid = blockIdx.x * 256 + threadIdx.x;
  for (int p = gid; p < PTOT; p += 512 * 256) {
    float f[6];
#pragma unroll
    for (int ch = 0; ch < 6; ++ch) f[ch] = feat[ch * PTOT + p];
    float h1[64];
#pragma unroll
    for (int o = 0; o < 64; ++o) {
      float z = b0[o];
#pragma unroll
      for (int i = 0; i < 6; ++i) z = fmaf(w0[o * 6 + i], f[i], z);
      h1[o] = fmaxf(fmaf(a1[o], z, c1[o]), 0.0f);
    }
    for (int o = 0; o < 64; o += 2) {
      float z0 = b1[o], z1 = b1[o + 1];
#pragma unroll
      for (int i = 0; i < 64; ++i) {
        z0 = fmaf(w1[o * 64 + i], h1[i], z0);
        z1 = fmaf(w1[(o + 1) * 64 + i], h1[i], z1);
      }
      float s0 = wave_sum(z0), q0 = wave_sum(z0 * z0);
      float s1 = wave_sum(z1), q1 = wave_sum(z1 * z1);
      if (lane == o)     { sp += s0; qp += q0; }
      if (lane == o + 1) { sp += s1; qp += q1; }
    }
  }
  atomicAdd(&stats[OFF_S2 + lane], sp);
  atomicAdd(&stats[OFF_Q2 + lane], qp);
}

// ---------------------------------------------------------------------------
// 5) layer-3 fused: stats + half-wave max -> zmax (pre-BN; a3>0 monotone).
// ---------------------------------------------------------------------------
__global__ __launch_bounds__(256, 2)
void mlp3f_kernel(const float* __restrict__ feat,
                  const float* __restrict__ w0, const float* __restrict__ b0,
                  const float* __restrict__ w1, const float* __restrict__ b1,
                  const float* __restrict__ w2, const float* __restrict__ b2,
                  const float* __restrict__ par, float* __restrict__ stats,
                  float* __restrict__ zmax) {
  const float* a1 = par + OFF_A1;
  const float* c1 = par + OFF_C1;
  const float* a2 = par + OFF_A2;
  const float* c2 = par + OFF_C2;
  const int lane = threadIdx.x & 63;
  float sp0 = 0.0f, qp0 = 0.0f;
  float sp1 = 0.0f, qp1 = 0.0f;
  int gid = blockIdx.x * 256 + threadIdx.x;
  for (int p = gid; p < PTOT; p += 512 * 256) {
    float f[6];
#pragma unroll
    for (int ch = 0; ch < 6; ++ch) f[ch] = feat[ch * PTOT + p];
    float h2[64];
#pragma unroll
    for (int o = 0; o < 64; ++o) h2[o] = b1[o];
    for (int i = 0; i < 64; ++i) {
      float z = b0[i];
#pragma unroll
      for (int ch = 0; ch < 6; ++ch) z = fmaf(w0[i * 6 + ch], f[ch], z);
      float h1i = fmaxf(fmaf(a1[i], z, c1[i]), 0.0f);
#pragma unroll
      for (int o = 0; o < 64; ++o) h2[o] = fmaf(w1[o * 64 + i], h1i, h2[o]);
    }
#pragma unroll
    for (int o = 0; o < 64; ++o) h2[o] = fmaxf(fmaf(a2[o], h2[o], c2[o]), 0.0f);

    const int g = p >> 5;
    for (int o = 0; o < 128; o += 2) {
      float z0 = b2[o], z1 = b2[o + 1];
#pragma unroll
      for (int i = 0; i < 64; ++i) {
        z0 = fmaf(w2[o * 64 + i], h2[i], z0);
        z1 = fmaf(w2[(o + 1) * 64 + i], h2[i], z1);
      }
      float s0 = wave_sum(z0), q0 = wave_sum(z0 * z0);
      float s1 = wave_sum(z1), q1 = wave_sum(z1 * z1);
      if (lane == (o & 63))       { if (o < 64) { sp0 += s0; qp0 += q0; } else { sp1 += s0; qp1 += q0; } }
      if (lane == ((o + 1) & 63)) { if (o < 64) { sp0 += s1; qp0 += q1; } else { sp1 += s1; qp1 += q1; } }
      float m0 = half_max(z0), m1 = half_max(z1);
      if ((lane & 31) == (o & 31))       zmax[g * 128 + o]     = m0;
      if ((lane & 31) == ((o + 1) & 31)) zmax[g * 128 + o + 1] = m1;
    }
  }
  atomicAdd(&stats[OFF_S3 + lane], sp0);
  atomicAdd(&stats[OFF_Q3 + lane], qp0);
  atomicAdd(&stats[OFF_S3 + 64 + lane], sp1);
  atomicAdd(&stats[OFF_Q3 + 64 + lane], qp1);
}

// ---------------------------------------------------------------------------
// 6) epilogue: out2[g][c] = relu(a3[c]*zmax[g][c] + c3[c])
// ---------------------------------------------------------------------------
__global__ __launch_bounds__(256, 4)
void final_out_kernel(const float* __restrict__ zmax, const float* __restrict__ par,
                      float* __restrict__ out2) {
  const float* a3 = par + OFF_A3;
  const float* c3 = par + OFF_C3;
  int idx = blockIdx.x * 256 + threadIdx.x;   // g*128 + c
  int c = idx & 127;
  out2[idx] = fmaxf(fmaf(a3[c], zmax[idx], c3[c]), 0.0f);
}

// ---------------------------------------------------------------------------
extern "C" void kernel_launch(void* const* d_in, const int* in_sizes, int n_in,
                              void* d_out, int out_size, void* d_ws, size_t ws_size,
                              hipStream_t stream) {
  const float* xyz = (const float*)d_in[0];
  const float* pts = (const float*)d_in[1];
  const float* w0  = (const float*)d_in[2];
  const float* b0  = (const float*)d_in[3];
  const float* g0  = (const float*)d_in[4];
  const float* be0 = (const float*)d_in[5];
  const float* w1  = (const float*)d_in[6];
  const float* b1  = (const float*)d_in[7];
  const float* g1  = (const float*)d_in[8];
  const float* be1 = (const float*)d_in[9];
  const float* w2  = (const float*)d_in[10];
  const float* b2  = (const float*)d_in[11];
  const float* g2  = (const float*)d_in[12];
  const float* be2 = (const float*)d_in[13];

  float* out  = (float*)d_out;
  float* nxz  = out;                 // (B,S,3)
  float* out2 = out + BB * SS * 3;   // (B,S,128)

  float* ws    = (float*)d_ws;
  float* stats = ws;                 // 512 floats, zeroed every call
  float* par   = ws;                 // params addressed via OFF_* macros
  float* zmax  = ws + OFF_ZMAX;
  float* feat  = ws + OFF_FEAT;
  float4* bpt  = (float4*)(ws + OFF_FEAT);  // fps scratch, freed before ballq

  hipMemsetAsync(stats, 0, 512 * sizeof(float), stream);

  fps_kernel<<<BB, 1024, 0, stream>>>(xyz, nxz, bpt);
  ballq_kernel<<<2048, 256, 0, stream>>>(xyz, pts, nxz, feat);

  mlp1s_kernel<<<256, 256, 0, stream>>>(feat, w0, b0, stats);
  fin_kernel<<<1, 64, 0, stream>>>(g0, be0, stats + OFF_S1, stats + OFF_Q1,
                                   par + OFF_A1, par + OFF_C1, 64);
  mlp2s_kernel<<<512, 256, 0, stream>>>(feat, w0, b0, w1, b1, par, stats);
  fin_kernel<<<1, 64, 0, stream>>>(g1, be1, stats + OFF_S2, stats + OFF_Q2,
                                   par + OFF_A2, par + OFF_C2, 64);
  mlp3f_kernel<<<512, 256, 0, stream>>>(feat, w0, b0, w1, b1, w2, b2, par, stats, zmax);
  fin_kernel<<<1, 128, 0, stream>>>(g2, be2, stats + OFF_S3, stats + OFF_Q3,
                                    par + OFF_A3, par + OFF_C3, 128);
  final_out_kernel<<<4096, 256, 0, stream>>>(zmax, par, out2);
}

// Round 7
// 3500.266 us; speedup vs baseline: 1.2933x; 1.2933x over previous
//
#include <hip/hip_runtime.h>
#include <stdint.h>

// Forbid mul+add contraction: distance arithmetic must match the numpy
// reference bit-for-bit (argmax / radius-compare are discontinuous).
// MLP math uses explicit fmaf() (exact FMA is fine; only ordering matters).
#pragma clang fp contract(off)

#define NPT   16384
#define BB    8
#define SS    1024
#define KSAMP 32
#define PTOT  (BB*SS*KSAMP)   // 262144
#define NGRP  (BB*SS)         // 8192
#define R2    0.04f
#define EPSBN 1e-5f
#define INV_M 3.814697265625e-06f   // 1/262144, exact power of two

// ws layout (floats)
#define OFF_S1 0
#define OFF_Q1 64
#define OFF_S2 128
#define OFF_Q2 192
#define OFF_S3 256    // 128
#define OFF_Q3 384    // 128
#define OFF_A1 512
#define OFF_C1 576
#define OFF_A2 640
#define OFF_C2 704
#define OFF_A3 768    // 128
#define OFF_C3 896    // 128
#define OFF_ZMAX 1024                  // 8192*128 = 1048576
#define OFF_FEAT (1024 + 1048576)      // 6*262144 = 1572864  (total ~10.5 MB)

// ---------------------------------------------------------------------------
// helpers
// ---------------------------------------------------------------------------
__device__ __forceinline__ float wave_sum(float v) {
#pragma unroll
  for (int off = 32; off; off >>= 1) v += __shfl_xor(v, off);
  return v;
}
__device__ __forceinline__ float half_max(float v) {
#pragma unroll
  for (int off = 16; off; off >>= 1) v = fmaxf(v, __shfl_xor(v, off));
  return v;
}

// ---------------------------------------------------------------------------
// 1) FPS brute force, LDS-resident xy + asm-pinned z.
//    History: R2/R3 (plain loads, VGPR=84) -> compiler REMATERIALIZED coord
//    loads inside the 1023-iter loop (192KB/iter L1 re-stream, 2.3ms). R4
//    (no restrict, VGPR=48) -> compiler SPILLED coords to scratch (3.0ms).
//    R5/R6 bucket-pruned -> latency-bound scaffolding (2.9-3.9ms).
//    This version: the 128KB xy stream comes from LDS at 128B/cyc (1024cyc
//    < 1536cyc VALU floor -> VALU-bound), and z[16] is produced by inline
//    asm global_load_dword -- an asm RESULT CANNOT BE REMATERIALIZED, and at
//    only 16 values (+16 d + temps ~ 90 VGPR < 128 cap of (1024,4)) there is
//    no spill pressure. d[16] is loop-carried RMW (always stayed in regs).
//    Arithmetic order & argmax tie-breaking identical to R2-R6 (passed 5x).
// ---------------------------------------------------------------------------
__global__ __launch_bounds__(1024, 4)
void fps_kernel(const float* __restrict__ xyz, float* __restrict__ newxyz) {
  const int b = blockIdx.x;
  const int t = threadIdx.x;
  const int lane = t & 63;
  const int w = t >> 6;                  // 16 waves
  const float* xb = xyz + (size_t)b * NPT * 3;

  __shared__ float2 xy[NPT];             // 128 KB
  __shared__ float rv[2][16];
  __shared__ int   ri[2][16];

  // stage x,y into LDS
  for (int p = t; p < NPT; p += 1024)
    xy[p] = make_float2(xb[3 * p], xb[3 * p + 1]);

  // z via asm loads (non-rematerializable), d init
  float z[16], d[16];
#pragma unroll
  for (int j = 0; j < 16; ++j) {
    const float* ap = xb + 3 * (j * 1024 + t) + 2;
    asm volatile("global_load_dword %0, %1, off" : "=v"(z[j]) : "v"(ap));
    d[j] = 1e10f;
  }
  // one waitcnt for all 16; "+v" outputs force every use of z[] after this
  asm volatile("s_waitcnt vmcnt(0)"
               : "+v"(z[0]), "+v"(z[1]), "+v"(z[2]), "+v"(z[3]),
                 "+v"(z[4]), "+v"(z[5]), "+v"(z[6]), "+v"(z[7]),
                 "+v"(z[8]), "+v"(z[9]), "+v"(z[10]), "+v"(z[11]),
                 "+v"(z[12]), "+v"(z[13]), "+v"(z[14]), "+v"(z[15]));

  if (t == 0) {                          // idx[0] = 0
    float* o = newxyz + (size_t)b * SS * 3;
    o[0] = xb[0]; o[1] = xb[1]; o[2] = xb[2];
  }
  int fi = 0;
  __syncthreads();                       // xy staged

  for (int it = 1; it < SS; ++it) {
    float2 cc = xy[fi];                  // LDS broadcast (free)
    float cx = cc.x, cy = cc.y;
    float cz = xb[3 * fi + 2];           // uniform L1 load
    float bv = -1.0f; int bi = 0x7fffffff;
#pragma unroll
    for (int j = 0; j < 16; ++j) {
      float2 p = xy[j * 1024 + t];       // ds_read_b64, 2-way bank = free
      float dx = p.x - cx, dy = p.y - cy, dz = z[j] - cz;
      float d2 = (dx * dx + dy * dy) + dz * dz;   // numpy order, no fma
      float dm = fminf(d[j], d2);
      d[j] = dm;
      if (dm > bv) { bv = dm; bi = j * 1024 + t; } // strict > => lowest j
    }
#pragma unroll
    for (int off = 32; off >= 1; off >>= 1) {      // wave argmax, tie->low idx
      float ov = __shfl_xor(bv, off);
      int   oi = __shfl_xor(bi, off);
      if (ov > bv || (ov == bv && oi < bi)) { bv = ov; bi = oi; }
    }
    const int buf = it & 1;
    if (lane == 0) { rv[buf][w] = bv; ri[buf][w] = bi; }
    __syncthreads();
    // single barrier: next iteration writes the OTHER buffer; its own
    // barrier orders those writes after these reads.
    float fv = rv[buf][0]; fi = ri[buf][0];
#pragma unroll
    for (int ww = 1; ww < 16; ++ww) {    // redundant merge (broadcast reads)
      float ov = rv[buf][ww]; int oi = ri[buf][ww];
      if (ov > fv || (ov == fv && oi < fi)) { fv = ov; fi = oi; }
    }
    if (t == 0) {
      float* o = newxyz + ((size_t)b * SS + it) * 3;
      o[0] = xb[3 * fi]; o[1] = xb[3 * fi + 1]; o[2] = xb[3 * fi + 2];
    }
  }
}

// ---------------------------------------------------------------------------
// 2) Ball query + gather (fused): one wave per centroid, ascending-index scan
//    with ballot == ref's sort+slice. feat is channel-major [6][PTOT].
// ---------------------------------------------------------------------------
__global__ __launch_bounds__(256, 2)
void ballq_kernel(const float* __restrict__ xyz, const float* __restrict__ pts,
                  const float* __restrict__ newxyz, float* __restrict__ feat) {
  const int lane = threadIdx.x & 63;
  const int c = blockIdx.x * 4 + (threadIdx.x >> 6);  // 0..8191
  const int b = c >> 10;
  const float* xb = xyz + (size_t)b * NPT * 3;
  const float* pb = pts + (size_t)b * NPT * 3;
  const float cx = newxyz[3 * c], cy = newxyz[3 * c + 1], cz = newxyz[3 * c + 2];
  const int base = c * KSAMP;
  const uint64_t ltm = (1ull << lane) - 1ull;

  int cnt = 0, firstp = 0;
  bool haveFirst = false;
  for (int p0 = 0; p0 < NPT && cnt < KSAMP; p0 += 64) {
    int p = p0 + lane;
    float px = xb[3 * p], py = xb[3 * p + 1], pz = xb[3 * p + 2];
    float dx = cx - px, dy = cy - py, dz = cz - pz;
    float sqr = (dx * dx + dy * dy) + dz * dz;
    bool in = (sqr <= R2);                          // !(sqr > r^2)
    uint64_t m = __ballot(in);
    if (!haveFirst && m) { firstp = p0 + (__ffsll((unsigned long long)m) - 1); haveFirst = true; }
    int rank = (int)__popcll(m & ltm);
    int slot = cnt + rank;
    if (in && slot < KSAMP) {
      int idx = base + slot;
      feat[0 * PTOT + idx] = px - cx;
      feat[1 * PTOT + idx] = py - cy;
      feat[2 * PTOT + idx] = pz - cz;
      feat[3 * PTOT + idx] = pb[3 * p];
      feat[4 * PTOT + idx] = pb[3 * p + 1];
      feat[5 * PTOT + idx] = pb[3 * p + 2];
    }
    cnt += (int)__popcll(m);
  }
  if (cnt < KSAMP) {  // pad with first in-ball point (center itself qualifies)
    int slot = cnt + lane;
    if (slot < KSAMP) {
      int idx = base + slot;
      float px = xb[3 * firstp], py = xb[3 * firstp + 1], pz = xb[3 * firstp + 2];
      feat[0 * PTOT + idx] = px - cx;
      feat[1 * PTOT + idx] = py - cy;
      feat[2 * PTOT + idx] = pz - cz;
      feat[3 * PTOT + idx] = pb[3 * firstp];
      feat[4 * PTOT + idx] = pb[3 * firstp + 1];
      feat[5 * PTOT + idx] = pb[3 * firstp + 2];
    }
  }
}

// ---------------------------------------------------------------------------
// 3) stats of layer-1 pre-activations.
// ---------------------------------------------------------------------------
__global__ __launch_bounds__(256, 2)
void mlp1s_kernel(const float* __restrict__ feat, const float* __restrict__ w0,
                  const float* __restrict__ b0, float* __restrict__ stats) {
  float s[64], q[64];
#pragma unroll
  for (int o = 0; o < 64; ++o) { s[o] = 0.0f; q[o] = 0.0f; }
  int gid = blockIdx.x * 256 + threadIdx.x;
  for (int p = gid; p < PTOT; p += 256 * 256) {
    float f[6];
#pragma unroll
    for (int ch = 0; ch < 6; ++ch) f[ch] = feat[ch * PTOT + p];
#pragma unroll
    for (int o = 0; o < 64; ++o) {
      float z = b0[o];
#pragma unroll
      for (int i = 0; i < 6; ++i) z = fmaf(w0[o * 6 + i], f[i], z);
      s[o] += z; q[o] = fmaf(z, z, q[o]);
    }
  }
  const int lane = threadIdx.x & 63;
#pragma unroll
  for (int o = 0; o < 64; ++o) { s[o] = wave_sum(s[o]); q[o] = wave_sum(q[o]); }
  __shared__ float ls[128];
  if (threadIdx.x < 128) ls[threadIdx.x] = 0.0f;
  __syncthreads();
  if (lane == 0) {
#pragma unroll
    for (int o = 0; o < 64; ++o) { atomicAdd(&ls[o], s[o]); atomicAdd(&ls[64 + o], q[o]); }
  }
  __syncthreads();
  if (threadIdx.x < 64) atomicAdd(&stats[OFF_S1 + threadIdx.x], ls[threadIdx.x]);
  else if (threadIdx.x < 128) atomicAdd(&stats[OFF_Q1 + threadIdx.x - 64], ls[threadIdx.x]);
}

// ---------------------------------------------------------------------------
// BN fold: a = g/sqrt(var+eps), c = be - a*mu   (h = relu(a*z + c))
// ---------------------------------------------------------------------------
__global__ void fin_kernel(const float* __restrict__ g, const float* __restrict__ be,
                           const float* __restrict__ s, const float* __restrict__ q,
                           float* __restrict__ A, float* __restrict__ C, int Cn) {
  int o = blockIdx.x * blockDim.x + threadIdx.x;
  if (o >= Cn) return;
  float mu = s[o] * INV_M;
  float var = q[o] * INV_M - mu * mu;
  float a = g[o] / sqrtf(var + EPSBN);
  A[o] = a;
  C[o] = be[o] - a * mu;
}

// ---------------------------------------------------------------------------
// 4) stats of layer-2 pre-activations.
// ---------------------------------------------------------------------------
__global__ __launch_bounds__(256, 2)
void mlp2s_kernel(const float* __restrict__ feat,
                  const float* __restrict__ w0, const float* __restrict__ b0,
                  const float* __restrict__ w1, const float* __restrict__ b1,
                  const float* __restrict__ par, float* __restrict__ stats) {
  const float* a1 = par + OFF_A1;
  const float* c1 = par + OFF_C1;
  const int lane = threadIdx.x & 63;
  float sp = 0.0f, qp = 0.0f;
  int gid = blockIdx.x * 256 + threadIdx.x;
  for (int p = gid; p < PTOT; p += 512 * 256) {
    float f[6];
#pragma unroll
    for (int ch = 0; ch < 6; ++ch) f[ch] = feat[ch * PTOT + p];
    float h1[64];
#pragma unroll
    for (int o = 0; o < 64; ++o) {
      float z = b0[o];
#pragma unroll
      for (int i = 0; i < 6; ++i) z = fmaf(w0[o * 6 + i], f[i], z);
      h1[o] = fmaxf(fmaf(a1[o], z, c1[o]), 0.0f);
    }
    for (int o = 0; o < 64; o += 2) {
      float z0 = b1[o], z1 = b1[o + 1];
#pragma unroll
      for (int i = 0; i < 64; ++i) {
        z0 = fmaf(w1[o * 64 + i], h1[i], z0);
        z1 = fmaf(w1[(o + 1) * 64 + i], h1[i], z1);
      }
      float s0 = wave_sum(z0), q0 = wave_sum(z0 * z0);
      float s1 = wave_sum(z1), q1 = wave_sum(z1 * z1);
      if (lane == o)     { sp += s0; qp += q0; }
      if (lane == o + 1) { sp += s1; qp += q1; }
    }
  }
  atomicAdd(&stats[OFF_S2 + lane], sp);
  atomicAdd(&stats[OFF_Q2 + lane], qp);
}

// ---------------------------------------------------------------------------
// 5) layer-3 fused: stats + half-wave max -> zmax (pre-BN; a3>0 monotone).
// ---------------------------------------------------------------------------
__global__ __launch_bounds__(256, 2)
void mlp3f_kernel(const float* __restrict__ feat,
                  const float* __restrict__ w0, const float* __restrict__ b0,
                  const float* __restrict__ w1, const float* __restrict__ b1,
                  const float* __restrict__ w2, const float* __restrict__ b2,
                  const float* __restrict__ par, float* __restrict__ stats,
                  float* __restrict__ zmax) {
  const float* a1 = par + OFF_A1;
  const float* c1 = par + OFF_C1;
  const float* a2 = par + OFF_A2;
  const float* c2 = par + OFF_C2;
  const int lane = threadIdx.x & 63;
  float sp0 = 0.0f, qp0 = 0.0f;
  float sp1 = 0.0f, qp1 = 0.0f;
  int gid = blockIdx.x * 256 + threadIdx.x;
  for (int p = gid; p < PTOT; p += 512 * 256) {
    float f[6];
#pragma unroll
    for (int ch = 0; ch < 6; ++ch) f[ch] = feat[ch * PTOT + p];
    float h2[64];
#pragma unroll
    for (int o = 0; o < 64; ++o) h2[o] = b1[o];
    for (int i = 0; i < 64; ++i) {
      float z = b0[i];
#pragma unroll
      for (int ch = 0; ch < 6; ++ch) z = fmaf(w0[i * 6 + ch], f[ch], z);
      float h1i = fmaxf(fmaf(a1[i], z, c1[i]), 0.0f);
#pragma unroll
      for (int o = 0; o < 64; ++o) h2[o] = fmaf(w1[o * 64 + i], h1i, h2[o]);
    }
#pragma unroll
    for (int o = 0; o < 64; ++o) h2[o] = fmaxf(fmaf(a2[o], h2[o], c2[o]), 0.0f);

    const int g = p >> 5;
    for (int o = 0; o < 128; o += 2) {
      float z0 = b2[o], z1 = b2[o + 1];
#pragma unroll
      for (int i = 0; i < 64; ++i) {
        z0 = fmaf(w2[o * 64 + i], h2[i], z0);
        z1 = fmaf(w2[(o + 1) * 64 + i], h2[i], z1);
      }
      float s0 = wave_sum(z0), q0 = wave_sum(z0 * z0);
      float s1 = wave_sum(z1), q1 = wave_sum(z1 * z1);
      if (lane == (o & 63))       { if (o < 64) { sp0 += s0; qp0 += q0; } else { sp1 += s0; qp1 += q0; } }
      if (lane == ((o + 1) & 63)) { if (o < 64) { sp0 += s1; qp0 += q1; } else { sp1 += s1; qp1 += q1; } }
      float m0 = half_max(z0), m1 = half_max(z1);
      if ((lane & 31) == (o & 31))       zmax[g * 128 + o]     = m0;
      if ((lane & 31) == ((o + 1) & 31)) zmax[g * 128 + o + 1] = m1;
    }
  }
  atomicAdd(&stats[OFF_S3 + lane], sp0);
  atomicAdd(&stats[OFF_Q3 + lane], qp0);
  atomicAdd(&stats[OFF_S3 + 64 + lane], sp1);
  atomicAdd(&stats[OFF_Q3 + 64 + lane], qp1);
}

// ---------------------------------------------------------------------------
// 6) epilogue: out2[g][c] = relu(a3[c]*zmax[g][c] + c3[c])
// ---------------------------------------------------------------------------
__global__ __launch_bounds__(256, 4)
void final_out_kernel(const float* __restrict__ zmax, const float* __restrict__ par,
                      float* __restrict__ out2) {
  const float* a3 = par + OFF_A3;
  const float* c3 = par + OFF_C3;
  int idx = blockIdx.x * 256 + threadIdx.x;   // g*128 + c
  int c = idx & 127;
  out2[idx] = fmaxf(fmaf(a3[c], zmax[idx], c3[c]), 0.0f);
}

// ---------------------------------------------------------------------------
extern "C" void kernel_launch(void* const* d_in, const int* in_sizes, int n_in,
                              void* d_out, int out_size, void* d_ws, size_t ws_size,
                              hipStream_t stream) {
  const float* xyz = (const float*)d_in[0];
  const float* pts = (const float*)d_in[1];
  const float* w0  = (const float*)d_in[2];
  const float* b0  = (const float*)d_in[3];
  const float* g0  = (const float*)d_in[4];
  const float* be0 = (const float*)d_in[5];
  const float* w1  = (const float*)d_in[6];
  const float* b1  = (const float*)d_in[7];
  const float* g1  = (const float*)d_in[8];
  const float* be1 = (const float*)d_in[9];
  const float* w2  = (const float*)d_in[10];
  const float* b2  = (const float*)d_in[11];
  const float* g2  = (const float*)d_in[12];
  const float* be2 = (const float*)d_in[13];

  float* out  = (float*)d_out;
  float* nxz  = out;                 // (B,S,3)
  float* out2 = out + BB * SS * 3;   // (B,S,128)

  float* ws    = (float*)d_ws;
  float* stats = ws;                 // 512 floats, zeroed every call
  float* par   = ws;                 // params addressed via OFF_* macros
  float* zmax  = ws + OFF_ZMAX;
  float* feat  = ws + OFF_FEAT;

  hipMemsetAsync(stats, 0, 512 * sizeof(float), stream);

  fps_kernel<<<BB, 1024, 0, stream>>>(xyz, nxz);
  ballq_kernel<<<2048, 256, 0, stream>>>(xyz, pts, nxz, feat);

  mlp1s_kernel<<<256, 256, 0, stream>>>(feat, w0, b0, stats);
  fin_kernel<<<1, 64, 0, stream>>>(g0, be0, stats + OFF_S1, stats + OFF_Q1,
                                   par + OFF_A1, par + OFF_C1, 64);
  mlp2s_kernel<<<512, 256, 0, stream>>>(feat, w0, b0, w1, b1, par, stats);
  fin_kernel<<<1, 64, 0, stream>>>(g1, be1, stats + OFF_S2, stats + OFF_Q2,
                                   par + OFF_A2, par + OFF_C2, 64);
  mlp3f_kernel<<<512, 256, 0, stream>>>(feat, w0, b0, w1, b1, w2, b2, par, stats, zmax);
  fin_kernel<<<1, 128, 0, stream>>>(g2, be2, stats + OFF_S3, stats + OFF_Q3,
                                    par + OFF_A3, par + OFF_C3, 128);
  final_out_kernel<<<4096, 256, 0, stream>>>(zmax, par, out2);
}

// Round 8
// 3140.065 us; speedup vs baseline: 1.4417x; 1.1147x over previous
//
#include <hip/hip_runtime.h>
#include <stdint.h>

// Forbid mul+add contraction: distance arithmetic must match the numpy
// reference bit-for-bit (argmax / radius-compare are discontinuous).
// MLP math uses explicit fmaf() (exact FMA is fine; only ordering matters).
#pragma clang fp contract(off)

#define NPT   16384
#define BB    8
#define SS    1024
#define KSAMP 32
#define PTOT  (BB*SS*KSAMP)   // 262144
#define NGRP  (BB*SS)         // 8192
#define R2    0.04f
#define EPSBN 1e-5f
#define INV_M 3.814697265625e-06f   // 1/262144, exact power of two

// ws layout (floats)
#define OFF_S1 0
#define OFF_Q1 64
#define OFF_S2 128
#define OFF_Q2 192
#define OFF_S3 256    // 128
#define OFF_Q3 384    // 128
#define OFF_A1 512
#define OFF_C1 576
#define OFF_A2 640
#define OFF_C2 704
#define OFF_A3 768    // 128
#define OFF_C3 896    // 128
#define OFF_ZMAX 1024                  // 8192*128 = 1048576
#define OFF_FEAT (1024 + 1048576)      // 6*262144 = 1572864  (total ~10.5 MB)
// fps z-scratch (8*16384 floats = 512 KB) ALIASES the feat region: fps
// completes before ballq writes feat (stream-ordered), so no extra ws.

// ---------------------------------------------------------------------------
// helpers
// ---------------------------------------------------------------------------
__device__ __forceinline__ float wave_sum(float v) {
#pragma unroll
  for (int off = 32; off; off >>= 1) v += __shfl_xor(v, off);
  return v;
}
__device__ __forceinline__ float half_max(float v) {
#pragma unroll
  for (int off = 16; off; off >>= 1) v = fmaxf(v, __shfl_xor(v, off));
  return v;
}

// ---------------------------------------------------------------------------
// 1) FPS brute force; all bulk state re-read every iteration BY DESIGN.
//    R2-R7 lesson: the allocator keeps ~16 loop-carried floats (d[]) in regs
//    and spills/remats anything more (VGPR stuck at 48-84, 2.3-3.0 ms). So:
//    - x,y live in LDS float2[16384] (128 KB; stride-1024 float2 reads are
//      2-way bank aliasing = free per m136), read per iter.
//    - z lives in a CONTIGUOUS global scratch zws (staged once): per-iter
//      stream is 64 KB/block of perfectly-coalesced dwords, L2-resident.
//      (R2 streamed stride-12 xyz: 33% line utilization ~ 576 KB/iter -
//      that, not VALU, was its 2.3us/iter.)
//    - d[16] is the only loop-carried register state.
//    Tail: wave butterfly carries (bv,bi,bz); cross-wave merge = 4-step
//    shuffle butterfly over 16 LDS partials (all lanes converge), winner's z
//    rides the shuffle so no dependent global cz load. One barrier/iter
//    (double-buffered partials, scheme proven R3-R7).
//    Arithmetic order & tie-breaking identical to R2-R7 (passed 6x).
// ---------------------------------------------------------------------------
__global__ __launch_bounds__(1024, 4)
void fps_kernel(const float* __restrict__ xyz, float* __restrict__ newxyz,
                float* __restrict__ zws) {
  const int b = blockIdx.x;
  const int t = threadIdx.x;
  const int lane = t & 63;
  const int w = t >> 6;                  // 16 waves
  const float* xb = xyz + (size_t)b * NPT * 3;
  float* zb = zws + (size_t)b * NPT;

  __shared__ float2 xy[NPT];             // 128 KB
  __shared__ float rv[2][16];
  __shared__ int   ri[2][16];
  __shared__ float rz[2][16];

  // stage: x,y -> LDS; z -> contiguous global scratch
  for (int p = t; p < NPT; p += 1024) {
    float px = xb[3 * p], py = xb[3 * p + 1], pz = xb[3 * p + 2];
    xy[p] = make_float2(px, py);
    zb[p] = pz;
  }

  float d[16];
#pragma unroll
  for (int j = 0; j < 16; ++j) d[j] = 1e10f;

  // initial centroid = point 0 (uniform scalar loads)
  float cx = xb[0], cy = xb[1], cz = xb[2];
  if (t == 0) {
    float* o = newxyz + (size_t)b * SS * 3;
    o[0] = cx; o[1] = cy; o[2] = cz;
  }
  __syncthreads();                       // xy/zb staged (barrier fences both)

  for (int it = 1; it < SS; ++it) {
    float bv = -1.0f; int bi = 0x7fffffff; float bz = 0.0f;
#pragma unroll
    for (int j = 0; j < 16; ++j) {
      int p = j * 1024 + t;
      float zj = zb[p];                  // coalesced dword, L2-hot
      float2 q = xy[p];                  // ds_read_b64, 2-way = free
      float dx = q.x - cx, dy = q.y - cy, dz = zj - cz;
      float d2 = (dx * dx + dy * dy) + dz * dz;   // numpy order, no fma
      float dm = fminf(d[j], d2);
      d[j] = dm;
      if (dm > bv) { bv = dm; bi = p; bz = zj; }  // strict > => lowest j
    }
    // wave argmax carrying (value, index, z); tie -> lower index
#pragma unroll
    for (int off = 32; off >= 1; off >>= 1) {
      float ov = __shfl_xor(bv, off);
      int   oi = __shfl_xor(bi, off);
      float oz = __shfl_xor(bz, off);
      if (ov > bv || (ov == bv && oi < bi)) { bv = ov; bi = oi; bz = oz; }
    }
    const int buf = it & 1;
    if (lane == 0) { rv[buf][w] = bv; ri[buf][w] = bi; rz[buf][w] = bz; }
    __syncthreads();
    // cross-wave merge: every lane loads partial (lane&15), 4-step butterfly
    // over the 16-slot space (4 copies across the wave) -> all lanes agree.
    int m = lane & 15;
    float fv = rv[buf][m]; int fi = ri[buf][m]; float fz = rz[buf][m];
#pragma unroll
    for (int off = 8; off >= 1; off >>= 1) {
      float ov = __shfl_xor(fv, off);
      int   oi = __shfl_xor(fi, off);
      float oz = __shfl_xor(fz, off);
      if (ov > fv || (ov == fv && oi < fi)) { fv = ov; fi = oi; fz = oz; }
    }
    float2 cc = xy[fi];                  // LDS broadcast (uniform addr)
    cx = cc.x; cy = cc.y; cz = fz;       // cz carried through shuffles
    if (t == 0) {
      float* o = newxyz + ((size_t)b * SS + it) * 3;
      o[0] = cx; o[1] = cy; o[2] = cz;
    }
    // single barrier/iter: next iteration writes the OTHER partial buffer;
    // its own barrier orders those writes after these reads.
  }
}

// ---------------------------------------------------------------------------
// 2) Ball query + gather (fused): one wave per centroid, ascending-index scan
//    with ballot == ref's sort+slice. feat is channel-major [6][PTOT].
// ---------------------------------------------------------------------------
__global__ __launch_bounds__(256, 2)
void ballq_kernel(const float* __restrict__ xyz, const float* __restrict__ pts,
                  const float* __restrict__ newxyz, float* __restrict__ feat) {
  const int lane = threadIdx.x & 63;
  const int c = blockIdx.x * 4 + (threadIdx.x >> 6);  // 0..8191
  const int b = c >> 10;
  const float* xb = xyz + (size_t)b * NPT * 3;
  const float* pb = pts + (size_t)b * NPT * 3;
  const float cx = newxyz[3 * c], cy = newxyz[3 * c + 1], cz = newxyz[3 * c + 2];
  const int base = c * KSAMP;
  const uint64_t ltm = (1ull << lane) - 1ull;

  int cnt = 0, firstp = 0;
  bool haveFirst = false;
  for (int p0 = 0; p0 < NPT && cnt < KSAMP; p0 += 64) {
    int p = p0 + lane;
    float px = xb[3 * p], py = xb[3 * p + 1], pz = xb[3 * p + 2];
    float dx = cx - px, dy = cy - py, dz = cz - pz;
    float sqr = (dx * dx + dy * dy) + dz * dz;
    bool in = (sqr <= R2);                          // !(sqr > r^2)
    uint64_t m = __ballot(in);
    if (!haveFirst && m) { firstp = p0 + (__ffsll((unsigned long long)m) - 1); haveFirst = true; }
    int rank = (int)__popcll(m & ltm);
    int slot = cnt + rank;
    if (in && slot < KSAMP) {
      int idx = base + slot;
      feat[0 * PTOT + idx] = px - cx;
      feat[1 * PTOT + idx] = py - cy;
      feat[2 * PTOT + idx] = pz - cz;
      feat[3 * PTOT + idx] = pb[3 * p];
      feat[4 * PTOT + idx] = pb[3 * p + 1];
      feat[5 * PTOT + idx] = pb[3 * p + 2];
    }
    cnt += (int)__popcll(m);
  }
  if (cnt < KSAMP) {  // pad with first in-ball point (center itself qualifies)
    int slot = cnt + lane;
    if (slot < KSAMP) {
      int idx = base + slot;
      float px = xb[3 * firstp], py = xb[3 * firstp + 1], pz = xb[3 * firstp + 2];
      feat[0 * PTOT + idx] = px - cx;
      feat[1 * PTOT + idx] = py - cy;
      feat[2 * PTOT + idx] = pz - cz;
      feat[3 * PTOT + idx] = pb[3 * firstp];
      feat[4 * PTOT + idx] = pb[3 * firstp + 1];
      feat[5 * PTOT + idx] = pb[3 * firstp + 2];
    }
  }
}

// ---------------------------------------------------------------------------
// 3) stats of layer-1 pre-activations.
// ---------------------------------------------------------------------------
__global__ __launch_bounds__(256, 2)
void mlp1s_kernel(const float* __restrict__ feat, const float* __restrict__ w0,
                  const float* __restrict__ b0, float* __restrict__ stats) {
  float s[64], q[64];
#pragma unroll
  for (int o = 0; o < 64; ++o) { s[o] = 0.0f; q[o] = 0.0f; }
  int gid = blockIdx.x * 256 + threadIdx.x;
  for (int p = gid; p < PTOT; p += 256 * 256) {
    float f[6];
#pragma unroll
    for (int ch = 0; ch < 6; ++ch) f[ch] = feat[ch * PTOT + p];
#pragma unroll
    for (int o = 0; o < 64; ++o) {
      float z = b0[o];
#pragma unroll
      for (int i = 0; i < 6; ++i) z = fmaf(w0[o * 6 + i], f[i], z);
      s[o] += z; q[o] = fmaf(z, z, q[o]);
    }
  }
  const int lane = threadIdx.x & 63;
#pragma unroll
  for (int o = 0; o < 64; ++o) { s[o] = wave_sum(s[o]); q[o] = wave_sum(q[o]); }
  __shared__ float ls[128];
  if (threadIdx.x < 128) ls[threadIdx.x] = 0.0f;
  __syncthreads();
  if (lane == 0) {
#pragma unroll
    for (int o = 0; o < 64; ++o) { atomicAdd(&ls[o], s[o]); atomicAdd(&ls[64 + o], q[o]); }
  }
  __syncthreads();
  if (threadIdx.x < 64) atomicAdd(&stats[OFF_S1 + threadIdx.x], ls[threadIdx.x]);
  else if (threadIdx.x < 128) atomicAdd(&stats[OFF_Q1 + threadIdx.x - 64], ls[threadIdx.x]);
}

// ---------------------------------------------------------------------------
// BN fold: a = g/sqrt(var+eps), c = be - a*mu   (h = relu(a*z + c))
// ---------------------------------------------------------------------------
__global__ void fin_kernel(const float* __restrict__ g, const float* __restrict__ be,
                           const float* __restrict__ s, const float* __restrict__ q,
                           float* __restrict__ A, float* __restrict__ C, int Cn) {
  int o = blockIdx.x * blockDim.x + threadIdx.x;
  if (o >= Cn) return;
  float mu = s[o] * INV_M;
  float var = q[o] * INV_M - mu * mu;
  float a = g[o] / sqrtf(var + EPSBN);
  A[o] = a;
  C[o] = be[o] - a * mu;
}

// ---------------------------------------------------------------------------
// 4) stats of layer-2 pre-activations.
// ---------------------------------------------------------------------------
__global__ __launch_bounds__(256, 2)
void mlp2s_kernel(const float* __restrict__ feat,
                  const float* __restrict__ w0, const float* __restrict__ b0,
                  const float* __restrict__ w1, const float* __restrict__ b1,
                  const float* __restrict__ par, float* __restrict__ stats) {
  const float* a1 = par + OFF_A1;
  const float* c1 = par + OFF_C1;
  const int lane = threadIdx.x & 63;
  float sp = 0.0f, qp = 0.0f;
  int gid = blockIdx.x * 256 + threadIdx.x;
  for (int p = gid; p < PTOT; p += 512 * 256) {
    float f[6];
#pragma unroll
    for (int ch = 0; ch < 6; ++ch) f[ch] = feat[ch * PTOT + p];
    float h1[64];
#pragma unroll
    for (int o = 0; o < 64; ++o) {
      float z = b0[o];
#pragma unroll
      for (int i = 0; i < 6; ++i) z = fmaf(w0[o * 6 + i], f[i], z);
      h1[o] = fmaxf(fmaf(a1[o], z, c1[o]), 0.0f);
    }
    for (int o = 0; o < 64; o += 2) {
      float z0 = b1[o], z1 = b1[o + 1];
#pragma unroll
      for (int i = 0; i < 64; ++i) {
        z0 = fmaf(w1[o * 64 + i], h1[i], z0);
        z1 = fmaf(w1[(o + 1) * 64 + i], h1[i], z1);
      }
      float s0 = wave_sum(z0), q0 = wave_sum(z0 * z0);
      float s1 = wave_sum(z1), q1 = wave_sum(z1 * z1);
      if (lane == o)     { sp += s0; qp += q0; }
      if (lane == o + 1) { sp += s1; qp += q1; }
    }
  }
  atomicAdd(&stats[OFF_S2 + lane], sp);
  atomicAdd(&stats[OFF_Q2 + lane], qp);
}

// ---------------------------------------------------------------------------
// 5) layer-3 fused: stats + half-wave max -> zmax (pre-BN; a3>0 monotone).
// ---------------------------------------------------------------------------
__global__ __launch_bounds__(256, 2)
void mlp3f_kernel(const float* __restrict__ feat,
                  const float* __restrict__ w0, const float* __restrict__ b0,
                  const float* __restrict__ w1, const float* __restrict__ b1,
                  const float* __restrict__ w2, const float* __restrict__ b2,
                  const float* __restrict__ par, float* __restrict__ stats,
                  float* __restrict__ zmax) {
  const float* a1 = par + OFF_A1;
  const float* c1 = par + OFF_C1;
  const float* a2 = par + OFF_A2;
  const float* c2 = par + OFF_C2;
  const int lane = threadIdx.x & 63;
  float sp0 = 0.0f, qp0 = 0.0f;
  float sp1 = 0.0f, qp1 = 0.0f;
  int gid = blockIdx.x * 256 + threadIdx.x;
  for (int p = gid; p < PTOT; p += 512 * 256) {
    float f[6];
#pragma unroll
    for (int ch = 0; ch < 6; ++ch) f[ch] = feat[ch * PTOT + p];
    float h2[64];
#pragma unroll
    for (int o = 0; o < 64; ++o) h2[o] = b1[o];
    for (int i = 0; i < 64; ++i) {
      float z = b0[i];
#pragma unroll
      for (int ch = 0; ch < 6; ++ch) z = fmaf(w0[i * 6 + ch], f[ch], z);
      float h1i = fmaxf(fmaf(a1[i], z, c1[i]), 0.0f);
#pragma unroll
      for (int o = 0; o < 64; ++o) h2[o] = fmaf(w1[o * 64 + i], h1i, h2[o]);
    }
#pragma unroll
    for (int o = 0; o < 64; ++o) h2[o] = fmaxf(fmaf(a2[o], h2[o], c2[o]), 0.0f);

    const int g = p >> 5;
    for (int o = 0; o < 128; o += 2) {
      float z0 = b2[o], z1 = b2[o + 1];
#pragma unroll
      for (int i = 0; i < 64; ++i) {
        z0 = fmaf(w2[o * 64 + i], h2[i], z0);
        z1 = fmaf(w2[(o + 1) * 64 + i], h2[i], z1);
      }
      float s0 = wave_sum(z0), q0 = wave_sum(z0 * z0);
      float s1 = wave_sum(z1), q1 = wave_sum(z1 * z1);
      if (lane == (o & 63))       { if (o < 64) { sp0 += s0; qp0 += q0; } else { sp1 += s0; qp1 += q0; } }
      if (lane == ((o + 1) & 63)) { if (o < 64) { sp0 += s1; qp0 += q1; } else { sp1 += s1; qp1 += q1; } }
      float m0 = half_max(z0), m1 = half_max(z1);
      if ((lane & 31) == (o & 31))       zmax[g * 128 + o]     = m0;
      if ((lane & 31) == ((o + 1) & 31)) zmax[g * 128 + o + 1] = m1;
    }
  }
  atomicAdd(&stats[OFF_S3 + lane], sp0);
  atomicAdd(&stats[OFF_Q3 + lane], qp0);
  atomicAdd(&stats[OFF_S3 + 64 + lane], sp1);
  atomicAdd(&stats[OFF_Q3 + 64 + lane], qp1);
}

// ---------------------------------------------------------------------------
// 6) epilogue: out2[g][c] = relu(a3[c]*zmax[g][c] + c3[c])
// ---------------------------------------------------------------------------
__global__ __launch_bounds__(256, 4)
void final_out_kernel(const float* __restrict__ zmax, const float* __restrict__ par,
                      float* __restrict__ out2) {
  const float* a3 = par + OFF_A3;
  const float* c3 = par + OFF_C3;
  int idx = blockIdx.x * 256 + threadIdx.x;   // g*128 + c
  int c = idx & 127;
  out2[idx] = fmaxf(fmaf(a3[c], zmax[idx], c3[c]), 0.0f);
}

// ---------------------------------------------------------------------------
extern "C" void kernel_launch(void* const* d_in, const int* in_sizes, int n_in,
                              void* d_out, int out_size, void* d_ws, size_t ws_size,
                              hipStream_t stream) {
  const float* xyz = (const float*)d_in[0];
  const float* pts = (const float*)d_in[1];
  const float* w0  = (const float*)d_in[2];
  const float* b0  = (const float*)d_in[3];
  const float* g0  = (const float*)d_in[4];
  const float* be0 = (const float*)d_in[5];
  const float* w1  = (const float*)d_in[6];
  const float* b1  = (const float*)d_in[7];
  const float* g1  = (const float*)d_in[8];
  const float* be1 = (const float*)d_in[9];
  const float* w2  = (const float*)d_in[10];
  const float* b2  = (const float*)d_in[11];
  const float* g2  = (const float*)d_in[12];
  const float* be2 = (const float*)d_in[13];

  float* out  = (float*)d_out;
  float* nxz  = out;                 // (B,S,3)
  float* out2 = out + BB * SS * 3;   // (B,S,128)

  float* ws    = (float*)d_ws;
  float* stats = ws;                 // 512 floats, zeroed every call
  float* par   = ws;                 // params addressed via OFF_* macros
  float* zmax  = ws + OFF_ZMAX;
  float* feat  = ws + OFF_FEAT;
  float* zws   = ws + OFF_FEAT;      // fps z-scratch, freed before ballq

  hipMemsetAsync(stats, 0, 512 * sizeof(float), stream);

  fps_kernel<<<BB, 1024, 0, stream>>>(xyz, nxz, zws);
  ballq_kernel<<<2048, 256, 0, stream>>>(xyz, pts, nxz, feat);

  mlp1s_kernel<<<256, 256, 0, stream>>>(feat, w0, b0, stats);
  fin_kernel<<<1, 64, 0, stream>>>(g0, be0, stats + OFF_S1, stats + OFF_Q1,
                                   par + OFF_A1, par + OFF_C1, 64);
  mlp2s_kernel<<<512, 256, 0, stream>>>(feat, w0, b0, w1, b1, par, stats);
  fin_kernel<<<1, 64, 0, stream>>>(g1, be1, stats + OFF_S2, stats + OFF_Q2,
                                   par + OFF_A2, par + OFF_C2, 64);
  mlp3f_kernel<<<512, 256, 0, stream>>>(feat, w0, b0, w1, b1, w2, b2, par, stats, zmax);
  fin_kernel<<<1, 128, 0, stream>>>(g2, be2, stats + OFF_S3, stats + OFF_Q3,
                                    par + OFF_A3, par + OFF_C3, 128);
  final_out_kernel<<<4096, 256, 0, stream>>>(zmax, par, out2);
}